// Round 17
// baseline (1607.480 us; speedup 1.0000x reference)
//
#include <hip/hip_runtime.h>
#include <math.h>

// Problem constants (fixed by the reference setup_inputs)
#define BATCH 32
#define CH    192
#define TFEAT 2048
#define TTXT  512
#define NEGINF (-1e9f)

#define ATTN_ELEMS ((size_t)BATCH * TFEAT * TTXT)   // 33,554,432
#define DUR_OFF    ATTN_ELEMS
#define NEG_OFF    (ATTN_ELEMS + (size_t)BATCH * TTXT)

__device__ __forceinline__ void gload_lds16(const float* g, float* l) {
  __builtin_amdgcn_global_load_lds(
      (const __attribute__((address_space(1))) void*)g,
      (__attribute__((address_space(3))) void*)l, 16, 0, 0);
}
__device__ __forceinline__ void gload_lds16h(const unsigned short* g,
                                             unsigned short* l) {
  __builtin_amdgcn_global_load_lds(
      (const __attribute__((address_space(1))) void*)g,
      (__attribute__((address_space(3))) void*)l, 16, 0, 0);
}

#define VMCNT(n) asm volatile("s_waitcnt vmcnt(" #n ")" ::: "memory")

__device__ __forceinline__ unsigned short f2b16(float f) {   // RNE bf16
  unsigned u = __float_as_uint(f);
  return (unsigned short)((u + 0x7FFFu + ((u >> 16) & 1u)) >> 16);
}

// ---------------------------------------------------------------------------
// Kernel P: W1[b,c,s] = m*exp(-2*logs), W2[b,c,s] = -0.5*exp(-2*logs)
// ---------------------------------------------------------------------------
__global__ void k_prep(const float* __restrict__ m_p,
                       const float* __restrict__ logs_p,
                       float* __restrict__ w1, float* __restrict__ w2) {
  int gid = blockIdx.x * 256 + threadIdx.x;    // 0 .. 3,145,727
  float m = m_p[gid];
  float l = logs_p[gid];
  float r = __expf(-2.0f * l);
  w1[gid] = m * r;
  w2[gid] = -0.5f * r;
}

// ---------------------------------------------------------------------------
// Kernel A: cadd[b][s] = sum_c(-0.5*log(2pi) - logs) + sum_c(-0.5*m^2*r)
// ---------------------------------------------------------------------------
__global__ void k_cadd(const float* __restrict__ m_p,
                       const float* __restrict__ logs_p,
                       float* __restrict__ cadd) {
  int gid = blockIdx.x * 256 + threadIdx.x;        // 0 .. 16383
  int b = gid >> 9, s = gid & (TTXT - 1);
  const float* mp = m_p    + (size_t)b * CH * TTXT + s;
  const float* lp = logs_p + (size_t)b * CH * TTXT + s;
  float acc = -0.5f * 1.8378770664093453f * (float)CH;   // -C/2 * log(2*pi)
  #pragma unroll 4
  for (int c = 0; c < CH; ++c) {
    float l = lp[(size_t)c * TTXT];
    float m = mp[(size_t)c * TTXT];
    float r = __expf(-2.0f * l);
    acc -= l + 0.5f * m * m * r;
  }
  cadd[gid] = acc;
}

// ---------------------------------------------------------------------------
// Kernel B (R17): fp32 GEMM, 512 threads, acc[8][8], tile 256x128.
// R16 model: at acc[8][4], LDS pipe 384cy/kk/CU vs VALU 256cy -> LDS-bound
// (VALUBusy 54%). acc[8][8] doubles FMA per B-read: LDS 576 vs VALU 512 ->
// ~balanced. 512 threads (NOT R14's 256: allocator gave 188 regs there);
// live set ~110. Half-kk rotation pipeline (R14's, proven structure).
// Per-output-element fma order unchanged (c asc) -> neg/negh bit-identical.
// Spill tripwire: WRITE_SIZE > 2e5 KB => revert.
// ---------------------------------------------------------------------------
#define BM 256
#define BN 128
#define BK 16

__global__ __launch_bounds__(512)
void k_gemm(const float* __restrict__ z_p,
            const float* __restrict__ w1g, const float* __restrict__ w2g,
            const float* __restrict__ cadd, float* __restrict__ neg,
            unsigned short* __restrict__ negh) {
  __shared__ float Az[2][BK][BM];    // 64 KB
  __shared__ float B1[2][BK][BN];    // 16 KB
  __shared__ float B2[2][BK][BN];    // 16 KB

  // chunked XCD swizzle (1024 blocks, 8 XCDs, 128 per chunk; bijective)
  int blk = (blockIdx.x & 7) * 128 + (blockIdx.x >> 3);
  int sb = blk & 3;            // TTXT/BN = 4
  int tb = (blk >> 2) & 7;     // TFEAT/BM = 8
  int b  = blk >> 5;
  int tid = threadIdx.x;
  int tx = tid & 15;           // col group: cols tx*4 and 64+tx*4
  int ty = tid >> 4;           // row group: 8 rows at ty*8 (0..31)
  int wid  = tid >> 6;         // wave 0..7
  int lane = tid & 63;
  int lr = lane >> 5;          // row-within-pair (B staging)
  int lc = (lane & 31) * 4;    // col (float4 granularity, B staging)

  const float* zb  = z_p + (size_t)b * CH * TFEAT + (size_t)tb * BM;
  const float* w1b = w1g + (size_t)b * CH * TTXT  + (size_t)sb * BN;
  const float* w2b = w2g + (size_t)b * CH * TTXT  + (size_t)sb * BN;

  auto STAGE = [&](int buf, int ko) {
    // A: 2 contiguous 1KB rows per wave (row = 256 f32)
    #pragma unroll
    for (int i2 = 0; i2 < 2; ++i2) {
      int kr = ko * BK + 2 * wid + i2;
      gload_lds16(zb + (size_t)kr * TFEAT + lane * 4, &Az[buf][2 * wid + i2][0]);
    }
    // B: one gload covers 2 rows (512B each), pair-gather
    int kr = ko * BK + 2 * wid + lr;
    gload_lds16(w1b + (size_t)kr * TTXT + lc, &B1[buf][2 * wid][0]);
    gload_lds16(w2b + (size_t)kr * TTXT + lc, &B2[buf][2 * wid][0]);
  };

  float acc[8][8];
  #pragma unroll
  for (int i = 0; i < 8; ++i)
    #pragma unroll
    for (int j = 0; j < 8; ++j) acc[i][j] = 0.0f;

  float aA[8], aB[8];
  float h0p[4], h0q[4], h1p[4], h1q[4];

  auto LOADA = [&](float (&aa)[8], int cur, int kk) {
    float4 a0 = *(const float4*)&Az[cur][kk][ty * 8];
    float4 a1 = *(const float4*)&Az[cur][kk][ty * 8 + 4];
    aa[0]=a0.x; aa[1]=a0.y; aa[2]=a0.z; aa[3]=a0.w;
    aa[4]=a1.x; aa[5]=a1.y; aa[6]=a1.z; aa[7]=a1.w;
  };
  auto LOADH0 = [&](int cur, int kk) {
    float4 p = *(const float4*)&B1[cur][kk][tx * 4];
    float4 q = *(const float4*)&B2[cur][kk][tx * 4];
    h0p[0]=p.x; h0p[1]=p.y; h0p[2]=p.z; h0p[3]=p.w;
    h0q[0]=q.x; h0q[1]=q.y; h0q[2]=q.z; h0q[3]=q.w;
  };
  auto LOADH1 = [&](int cur, int kk) {
    float4 p = *(const float4*)&B1[cur][kk][64 + tx * 4];
    float4 q = *(const float4*)&B2[cur][kk][64 + tx * 4];
    h1p[0]=p.x; h1p[1]=p.y; h1p[2]=p.z; h1p[3]=p.w;
    h1q[0]=q.x; h1q[1]=q.y; h1q[2]=q.z; h1q[3]=q.w;
  };
  auto FMAH0 = [&](const float (&aa)[8]) {
    #pragma unroll
    for (int i = 0; i < 8; ++i)
      #pragma unroll
      for (int j = 0; j < 4; ++j)
        acc[i][j] = fmaf(aa[i], fmaf(aa[i], h0q[j], h0p[j]), acc[i][j]);
  };
  auto FMAH1 = [&](const float (&aa)[8]) {
    #pragma unroll
    for (int i = 0; i < 8; ++i)
      #pragma unroll
      for (int j = 0; j < 4; ++j)
        acc[i][4 + j] = fmaf(aa[i], fmaf(aa[i], h1q[j], h1p[j]), acc[i][4 + j]);
  };

  STAGE(0, 0);
  VMCNT(0);
  __builtin_amdgcn_s_barrier();

  for (int ko = 0; ko < CH / BK; ++ko) {
    int cur = ko & 1;
    if (ko + 1 < CH / BK) STAGE(cur ^ 1, ko + 1);   // prefetch next tile

    LOADA(aA, cur, 0); LOADH0(cur, 0);
    #pragma unroll
    for (int kk = 0; kk < BK; kk += 2) {
      LOADH1(cur, kk);                   // hides under FMAH0(aA)
      FMAH0(aA);
      __builtin_amdgcn_sched_barrier(0);
      LOADA(aB, cur, kk + 1); LOADH0(cur, kk + 1);
      FMAH1(aA);
      __builtin_amdgcn_sched_barrier(0);
      LOADH1(cur, kk + 1);
      FMAH0(aB);
      __builtin_amdgcn_sched_barrier(0);
      if (kk + 2 < BK) { LOADA(aA, cur, kk + 2); LOADH0(cur, kk + 2); }
      FMAH1(aB);
      __builtin_amdgcn_sched_barrier(0);
    }
    VMCNT(0);                            // next tile landed (had whole compute)
    __builtin_amdgcn_s_barrier();
  }

  // epilogue: rows tb*256 + ty*8 + i; cols sb*128 + {tx*4, 64+tx*4}
  const float* cb = cadd + b * TTXT + sb * BN;
  float4 cb0 = *(const float4*)(cb + tx * 4);
  float4 cb1 = *(const float4*)(cb + 64 + tx * 4);
  float c0[4] = {cb0.x, cb0.y, cb0.z, cb0.w};
  float c1[4] = {cb1.x, cb1.y, cb1.z, cb1.w};
  float* ob = neg + (size_t)b * TFEAT * TTXT
            + (size_t)(tb * BM + ty * 8) * TTXT + sb * BN;
  // re-tiled bf16 shadow: window iw = tb*16 + (ty>>1), slice 2sb / 2sb+1,
  // row-in-window r = (ty&1)*8 + i, col-in-slice = tx*4
  unsigned short* oh = negh
      + (((size_t)b * 128 + tb * 16 + (ty >> 1)) * 8 + 2 * sb) * 1024
      + (ty & 1) * 512 + tx * 4;
  #pragma unroll
  for (int i = 0; i < 8; ++i) {
    float4 o0 = {acc[i][0] + c0[0], acc[i][1] + c0[1], acc[i][2] + c0[2], acc[i][3] + c0[3]};
    float4 o1 = {acc[i][4] + c1[0], acc[i][5] + c1[1], acc[i][6] + c1[2], acc[i][7] + c1[3]};
    float* row = ob + (size_t)i * TTXT;
    *(float4*)(row + tx * 4)      = o0;
    *(float4*)(row + 64 + tx * 4) = o1;
    ushort4 h0 = {f2b16(o0.x), f2b16(o0.y), f2b16(o0.z), f2b16(o0.w)};
    ushort4 h1 = {f2b16(o1.x), f2b16(o1.y), f2b16(o1.z), f2b16(o1.w)};
    *(ushort4*)(oh + (size_t)i * 64)        = h0;
    *(ushort4*)(oh + 1024 + (size_t)i * 64) = h1;
  }
}

// ---------------------------------------------------------------------------
// Kernel C: skewed-wavefront DP — UNCHANGED from R16 (~290us; bytes/segment/
// barrier theories all refuted; frozen while k_gemm is the top cost).
// ---------------------------------------------------------------------------
#define KROWS 16
#define NWIN  (TFEAT / KROWS)     // 128 windows
#define NMASKW (TTXT / KROWS)     // 32 masked windows

__device__ __forceinline__ float dpp_shr1(float v) {
  return __int_as_float(__builtin_amdgcn_update_dpp(
      __float_as_int(v), __float_as_int(v), 0x138 /*wave_shr:1*/, 0xF, 0xF, false));
}

__global__ __launch_bounds__(512, 1)
void k_dp(const unsigned short* __restrict__ negh, float* __restrict__ dur,
          int* __restrict__ idx_out, const float* __restrict__ x_mask,
          unsigned long long* __restrict__ gbits_all) {
  __shared__ unsigned short ringh[8][4][KROWS * 64];  // 65536 B per-wave ring
  __shared__ float bndlds[3][8][KROWS];               //  1536 B boundary ring
  int b = blockIdx.x, tid = threadIdx.x;
  int lane = tid & 63, w = tid >> 6;
  // wave w's slice stream: blocks of 1024 ushorts per (window, wave)
  const unsigned short* nb =
      negh + (((size_t)b * NWIN) * 8 + w) * 1024 + lane * 8;
  unsigned long long* gbits = gbits_all + (size_t)b * 8 * TFEAT;  // [8][2048]

  if (tid < 3 * 8 * KROWS) ((float*)bndlds)[tid] = NEGINF;

  auto stage = [&](int j) {               // 2 contiguous 1KB loads
    int slot = j & 3;
    const unsigned short* s0 = nb + (size_t)j * 8 * 1024;
    gload_lds16h(s0,       &ringh[w][slot][0]);
    gload_lds16h(s0 + 512, &ringh[w][slot][512]);
  };

  stage(0); stage(1); stage(2);
  __syncthreads();                        // drains prologue loads + bndlds init

  float prev = NEGINF;
  for (int p = 0; p < NWIN + 8; ++p) {
    int i = p - w;                        // this wave's window this phase
    if (i >= 0 && i + 3 < NWIN) { stage(i + 3); VMCNT(6); }
    else if (i >= 0) {
      int rem = NWIN - 1 - i;
      if (rem == 2)      VMCNT(4);
      else if (rem == 1) VMCNT(2);
      else               VMCNT(0);
    }
    asm volatile("s_waitcnt lgkmcnt(0)" ::: "memory");
    __builtin_amdgcn_s_barrier();         // bndlds(prev phase) visible
    __builtin_amdgcn_sched_barrier(0);

    if (i >= 0 && i < NWIN) {
      // hoisted boundary values (wave-uniform)
      float s_bnd[KROWS];
      if (w > 0) {
        float v   = bndlds[i % 3][w - 1][lane & 15];
        float v15 = bndlds[(i + 2) % 3][w - 1][15];
        s_bnd[0] = __int_as_float(__builtin_amdgcn_readfirstlane(__float_as_int(v15)));
        #pragma unroll
        for (int r = 1; r < KROWS; ++r)
          s_bnd[r] = __int_as_float(__builtin_amdgcn_readlane(__float_as_int(v), r - 1));
      } else {
        #pragma unroll
        for (int r = 0; r < KROWS; ++r) s_bnd[r] = NEGINF;
        if (i == 0) s_bnd[0] = 0.0f;      // y==0, x==0 edge
      }
      // own-slice nf: bf16 -> f32 exact decode
      float cur[KROWS];
      #pragma unroll
      for (int r = 0; r < KROWS; ++r)
        cur[r] = __uint_as_float((unsigned)ringh[w][i & 3][r * 64 + lane] << 16);

      int y0 = i * KROWS;
      bool masked = (i < NMASKW);
      unsigned keep_lo = 0, keep_hi = 0;
      float bkeep = 0.0f;
      unsigned long long andm = (w == 0) ? ~1ull : ~0ull;   // x==0 never moves
      #pragma unroll
      for (int r = 0; r < KROWS; ++r) {
        float upd = dpp_shr1(prev);
        float up = (lane == 0) ? s_bnd[r] : upd;
        bool force = masked && (tid == y0 + r);
        bool gt = prev < up;
        unsigned long long m = __ballot(force || gt) & andm;  // uniform
        bool mine = (lane == r);
        keep_lo = mine ? (unsigned)m : keep_lo;
        keep_hi = mine ? (unsigned)(m >> 32) : keep_hi;
        float vc = force ? NEGINF : prev;
        prev = fmaxf(vc, up) + cur[r];
        float v63 = __int_as_float(
            __builtin_amdgcn_readlane(__float_as_int(prev), 63));  // uniform
        bkeep = mine ? v63 : bkeep;
      }
      if (lane < KROWS) {                 // one exec toggle per window
        bndlds[i % 3][w][lane] = bkeep;
        gbits[(size_t)w * TFEAT + y0 + lane] =
            ((unsigned long long)keep_hi << 32) | keep_lo;   // 128B contiguous
      }
    }
  }
  VMCNT(0);
  __syncthreads();                        // gbits stores drained + visible

  // ---- serial backtrack (tid 0), 16-deep register ring over global bits.
  if (tid == 0) {
    const float* xm = x_mask + (size_t)b * TTXT;
    int idx = TTXT - 1, cnt = 0;
    unsigned long long ua[16], ub[16]; int qi[16];
    #pragma unroll
    for (int q16 = 0; q16 < 16; ++q16) {  // rows 2032..2047 (slot = y&15)
      ua[q16] = gbits[(size_t)7 * TFEAT + 2032 + q16];
      ub[q16] = gbits[(size_t)6 * TFEAT + 2032 + q16];
      qi[q16] = 7;
    }
    for (int yb = 2032; yb >= 16; yb -= 16) {
      #pragma unroll
      for (int jj = 15; jj >= 0; --jj) {
        int y = yb + jj;                  // slot = jj (yb % 16 == 0)
        unsigned long long w64 = ((idx >> 6) == qi[jj]) ? ua[jj] : ub[jj];
        idx_out[b * TFEAT + y] = idx;
        cnt++;
        if ((w64 >> (idx & 63)) & 1ull) {
          dur[b * TTXT + idx] = (float)cnt * xm[idx];
          cnt = 0; idx--;
        }
        int q = idx >> 6;                 // refill slot jj for row y-16
        int qm = q > 0 ? q - 1 : 0;
        ua[jj] = gbits[(size_t)q  * TFEAT + (y - 16)];
        ub[jj] = gbits[(size_t)qm * TFEAT + (y - 16)];
        qi[jj] = q;
      }
    }
    #pragma unroll
    for (int jj = 15; jj >= 0; --jj) {    // tail rows 15..0
      int y = jj;
      unsigned long long w64 = ((idx >> 6) == qi[jj]) ? ua[jj] : ub[jj];
      idx_out[b * TFEAT + y] = idx;
      cnt++;
      if ((w64 >> (idx & 63)) & 1ull) {
        dur[b * TTXT + idx] = (float)cnt * xm[idx];
        cnt = 0; idx--;
      }
    }
    dur[b * TTXT] = (float)cnt * xm[0];   // idx == 0 tail run
  }
}

// ---------------------------------------------------------------------------
// Kernel D: attn[b,y,x] = (x == idx[y]) * x_mask[b,x] * y_mask[b,y]
// ---------------------------------------------------------------------------
__global__ void k_attn(const int* __restrict__ idx_arr,
                       const float* __restrict__ x_mask,
                       const float* __restrict__ y_mask,
                       float* __restrict__ attn) {
  size_t gid = (size_t)blockIdx.x * 256 + threadIdx.x;
  size_t e = gid << 2;               // 4 floats per thread
  int b = (int)(e >> 20);            // TFEAT*TTXT = 2^20
  int rem = (int)(e & 1048575u);
  int y = rem >> 9;
  int x0 = rem & 511;
  int idx = idx_arr[b * TFEAT + y];
  float4 v = {0.f, 0.f, 0.f, 0.f};
  int d = idx - x0;
  if (d >= 0 && d < 4) {
    ((float*)&v)[d] = x_mask[b * TTXT + idx] * y_mask[b * TFEAT + y];
  }
  *(float4*)(attn + e) = v;
}

// ---------------------------------------------------------------------------
extern "C" void kernel_launch(void* const* d_in, const int* in_sizes, int n_in,
                              void* d_out, int out_size, void* d_ws, size_t ws_size,
                              hipStream_t stream) {
  const float* z_p    = (const float*)d_in[0];
  const float* m_p    = (const float*)d_in[1];
  const float* logs_p = (const float*)d_in[2];
  const float* x_mask = (const float*)d_in[3];
  const float* y_mask = (const float*)d_in[4];

  float* out  = (float*)d_out;
  float* attn = out;
  float* dur  = out + DUR_OFF;
  float* neg  = out + NEG_OFF;

  // scratch in the attn region (fully rewritten by k_attn at the end):
  //   w1s/w2s (24MB, dead after k_gemm) | gbits (4MB) | negh (64MB bf16)
  float* w1s = attn;
  float* w2s = attn + (size_t)BATCH * CH * TTXT;          // 3,145,728 floats
  unsigned long long* gbits =
      (unsigned long long*)(attn + 2 * (size_t)BATCH * CH * TTXT);
  unsigned short* negh =
      (unsigned short*)(attn + 2 * (size_t)BATCH * CH * TTXT + 1048576);

  // workspace: cadd (64 KiB) + idx array (256 KiB)
  float* cadd = (float*)d_ws;
  int*   idxa = (int*)((char*)d_ws + 65536);

  k_prep<<<(BATCH * CH * TTXT) / 256, 256, 0, stream>>>(m_p, logs_p, w1s, w2s);
  k_cadd<<<(BATCH * TTXT) / 256, 256, 0, stream>>>(m_p, logs_p, cadd);
  k_gemm<<<BATCH * (TFEAT / BM) * (TTXT / BN), 512, 0, stream>>>(z_p, w1s, w2s, cadd, neg, negh);
  k_dp<<<BATCH, 512, 0, stream>>>(negh, dur, idxa, x_mask, gbits);
  k_attn<<<(int)(ATTN_ELEMS / 4 / 256), 256, 0, stream>>>(idxa, x_mask, y_mask, attn);
}

// Round 18
// 771.534 us; speedup vs baseline: 2.0835x; 2.0835x over previous
//
#include <hip/hip_runtime.h>
#include <math.h>

// Problem constants (fixed by the reference setup_inputs)
#define BATCH 32
#define CH    192
#define TFEAT 2048
#define TTXT  512
#define NEGINF (-1e9f)

#define ATTN_ELEMS ((size_t)BATCH * TFEAT * TTXT)   // 33,554,432
#define DUR_OFF    ATTN_ELEMS
#define NEG_OFF    (ATTN_ELEMS + (size_t)BATCH * TTXT)

__device__ __forceinline__ void gload_lds16(const float* g, float* l) {
  __builtin_amdgcn_global_load_lds(
      (const __attribute__((address_space(1))) void*)g,
      (__attribute__((address_space(3))) void*)l, 16, 0, 0);
}
__device__ __forceinline__ void gload_lds16h(const unsigned short* g,
                                             unsigned short* l) {
  __builtin_amdgcn_global_load_lds(
      (const __attribute__((address_space(1))) void*)g,
      (__attribute__((address_space(3))) void*)l, 16, 0, 0);
}

#define VMCNT(n) asm volatile("s_waitcnt vmcnt(" #n ")" ::: "memory")

__device__ __forceinline__ unsigned short f2b16(float f) {   // RNE bf16
  unsigned u = __float_as_uint(f);
  return (unsigned short)((u + 0x7FFFu + ((u >> 16) & 1u)) >> 16);
}

// ---------------------------------------------------------------------------
// Kernel P: w1h = bf16(m*exp(-2*logs)), w2h = bf16(-0.5*exp(-2*logs))
// bf16 weights: k_gemm's LDS B-traffic halves (R17 post-mortem: LDS-bound).
// ---------------------------------------------------------------------------
__global__ void k_prep(const float* __restrict__ m_p,
                       const float* __restrict__ logs_p,
                       unsigned short* __restrict__ w1h,
                       unsigned short* __restrict__ w2h) {
  int gid = blockIdx.x * 256 + threadIdx.x;    // 0 .. 3,145,727
  float m = m_p[gid];
  float l = logs_p[gid];
  float r = __expf(-2.0f * l);
  w1h[gid] = f2b16(m * r);
  w2h[gid] = f2b16(-0.5f * r);
}

// ---------------------------------------------------------------------------
// Kernel A: cadd[b][s] = sum_c(-0.5*log(2pi) - logs) + sum_c(-0.5*m^2*r)
// (full f32 precision — unchanged)
// ---------------------------------------------------------------------------
__global__ void k_cadd(const float* __restrict__ m_p,
                       const float* __restrict__ logs_p,
                       float* __restrict__ cadd) {
  int gid = blockIdx.x * 256 + threadIdx.x;        // 0 .. 16383
  int b = gid >> 9, s = gid & (TTXT - 1);
  const float* mp = m_p    + (size_t)b * CH * TTXT + s;
  const float* lp = logs_p + (size_t)b * CH * TTXT + s;
  float acc = -0.5f * 1.8378770664093453f * (float)CH;   // -C/2 * log(2*pi)
  #pragma unroll 4
  for (int c = 0; c < CH; ++c) {
    float l = lp[(size_t)c * TTXT];
    float m = mp[(size_t)c * TTXT];
    float r = __expf(-2.0f * l);
    acc -= l + 0.5f * m * m * r;
  }
  cadd[gid] = acc;
}

// ---------------------------------------------------------------------------
// Kernel B (R18): fp32 GEMM, 512 thr, acc[8][4] (register-optimal: R17
// proved acc>32 regs spills at the 128 cap). Change vs R16: B operands
// (w1/w2) staged and held in LDS as BF16 — per-kk LDS traffic 64B->48B per
// thread (~376cy -> ~288cy per CU), decode = 1 shift/elem (+8 VALU) ->
// LDS/VALU balanced at ~288/288. FMA form & order per output element
// unchanged; weights are bf16-rounded (neg err ~0.4% rel << threshold).
// Spill tripwire: WRITE_SIZE > 2.5e5 KB => revert to R16.
// ---------------------------------------------------------------------------
#define BM 128
#define BN 128
#define BK 16

struct Frag { float a[8]; float p[4]; float q[4]; };

__global__ __launch_bounds__(512)
void k_gemm(const float* __restrict__ z_p,
            const unsigned short* __restrict__ w1g,
            const unsigned short* __restrict__ w2g,
            const float* __restrict__ cadd, float* __restrict__ neg,
            unsigned short* __restrict__ negh) {
  __shared__ float Az[2][BK][BM];             // 16 KB
  __shared__ unsigned short B1h[2][BK][BN];   //  8 KB
  __shared__ unsigned short B2h[2][BK][BN];   //  8 KB

  // chunked XCD swizzle (2048 blocks, 8 XCDs, 256 per chunk; bijective)
  int blk = (blockIdx.x & 7) * 256 + (blockIdx.x >> 3);
  int sb = blk & 3;            // TTXT/BN = 4
  int tb = (blk >> 2) & 15;    // TFEAT/BM = 16
  int b  = blk >> 6;
  int tid = threadIdx.x;
  int tx = tid & 31;           // col group: 4 cols at tx*4
  int ty = tid >> 5;           // row group: 8 rows at ty*8  (0..15)
  int wid  = tid >> 6;         // wave 0..7
  int lane = tid & 63;
  int lr = lane >> 5;          // row-within-pair (A staging)
  int lc = (lane & 31) * 4;    // col (float4 granularity, A staging)

  const float* zb = z_p + (size_t)b * CH * TFEAT + (size_t)tb * BM;
  const unsigned short* w1b = w1g + (size_t)b * CH * TTXT + sb * BN;
  const unsigned short* w2b = w2g + (size_t)b * CH * TTXT + sb * BN;

  auto STAGE = [&](int buf, int ko) {
    // A: wave wid stages rows {2wid, 2wid+1} (1 gload, 1KB)
    int kr = ko * BK + 2 * wid + lr;
    gload_lds16(zb + (size_t)kr * TFEAT + lc, &Az[buf][2 * wid][0]);
    // B (bf16): waves 0-3 -> B1h rows 4w..4w+3; waves 4-7 -> B2h (1KB each)
    int w4 = wid & 3;
    int krh = ko * BK + 4 * w4 + (lane >> 4);
    int ch = (lane & 15) * 8;            // 8 ushorts = 16B per lane
    if (wid < 4)
      gload_lds16h(w1b + (size_t)krh * TTXT + ch, &B1h[buf][4 * w4][0]);
    else
      gload_lds16h(w2b + (size_t)krh * TTXT + ch, &B2h[buf][4 * w4][0]);
  };
  auto LOADF = [&](Frag& f, int cur, int kk) {
    float4 a0 = *(const float4*)&Az[cur][kk][ty * 8];
    float4 a1 = *(const float4*)&Az[cur][kk][ty * 8 + 4];
    uint2 pu = *(const uint2*)&B1h[cur][kk][tx * 4];
    uint2 qu = *(const uint2*)&B2h[cur][kk][tx * 4];
    f.a[0]=a0.x; f.a[1]=a0.y; f.a[2]=a0.z; f.a[3]=a0.w;
    f.a[4]=a1.x; f.a[5]=a1.y; f.a[6]=a1.z; f.a[7]=a1.w;
    f.p[0] = __uint_as_float(pu.x << 16);
    f.p[1] = __uint_as_float(pu.x & 0xFFFF0000u);
    f.p[2] = __uint_as_float(pu.y << 16);
    f.p[3] = __uint_as_float(pu.y & 0xFFFF0000u);
    f.q[0] = __uint_as_float(qu.x << 16);
    f.q[1] = __uint_as_float(qu.x & 0xFFFF0000u);
    f.q[2] = __uint_as_float(qu.y << 16);
    f.q[3] = __uint_as_float(qu.y & 0xFFFF0000u);
  };

  float acc[8][4];
  #pragma unroll
  for (int i = 0; i < 8; ++i)
    #pragma unroll
    for (int j = 0; j < 4; ++j) acc[i][j] = 0.0f;

  auto FMAF = [&](const Frag& f) {
    #pragma unroll
    for (int i = 0; i < 8; ++i)
      #pragma unroll
      for (int j = 0; j < 4; ++j)
        acc[i][j] = fmaf(f.a[i], fmaf(f.a[i], f.q[j], f.p[j]), acc[i][j]);
  };

  STAGE(0, 0);
  VMCNT(0);
  __builtin_amdgcn_s_barrier();

  for (int ko = 0; ko < CH / BK; ++ko) {
    int cur = ko & 1;
    if (ko + 1 < CH / BK) STAGE(cur ^ 1, ko + 1);   // prefetch next tile

    Frag f0, f1;
    LOADF(f0, cur, 0);
    #pragma unroll
    for (int kk = 0; kk < BK; kk += 2) {
      LOADF(f1, cur, kk + 1);            // reads hide under FMAF(f0)
      FMAF(f0);
      __builtin_amdgcn_sched_barrier(0);
      if (kk + 2 < BK) LOADF(f0, cur, kk + 2);
      FMAF(f1);
      __builtin_amdgcn_sched_barrier(0);
    }
    VMCNT(0);                            // next tile landed (had whole compute)
    __builtin_amdgcn_s_barrier();
  }

  float4 cb4 = *(const float4*)(cadd + b * TTXT + sb * BN + tx * 4);
  float c0[4] = {cb4.x, cb4.y, cb4.z, cb4.w};
  float* ob = neg + (size_t)b * TFEAT * TTXT
            + (size_t)(tb * BM + ty * 8) * TTXT + sb * BN;
  // re-tiled bf16 shadow (R16 mapping, verified): window iw = tb*8+(ty>>1),
  // slice = 2sb+(tx>>4), row r = (ty&1)*8+i, col = (tx&15)*4
  unsigned short* oh = negh
      + (((size_t)b * 128 + tb * 8 + (ty >> 1)) * 8 + 2 * sb + (tx >> 4)) * 1024
      + (size_t)((ty & 1) * 8) * 64 + (tx & 15) * 4;
  #pragma unroll
  for (int i = 0; i < 8; ++i) {
    float4 o = {acc[i][0] + c0[0], acc[i][1] + c0[1], acc[i][2] + c0[2], acc[i][3] + c0[3]};
    *(float4*)(ob + (size_t)i * TTXT + tx * 4) = o;
    ushort4 h = {f2b16(o.x), f2b16(o.y), f2b16(o.z), f2b16(o.w)};
    *(ushort4*)(oh + (size_t)i * 64) = h;
  }
}

// ---------------------------------------------------------------------------
// Kernel C: skewed-wavefront DP — UNCHANGED from R16 (~290us, frozen).
// ---------------------------------------------------------------------------
#define KROWS 16
#define NWIN  (TFEAT / KROWS)     // 128 windows
#define NMASKW (TTXT / KROWS)     // 32 masked windows

__device__ __forceinline__ float dpp_shr1(float v) {
  return __int_as_float(__builtin_amdgcn_update_dpp(
      __float_as_int(v), __float_as_int(v), 0x138 /*wave_shr:1*/, 0xF, 0xF, false));
}

__global__ __launch_bounds__(512, 1)
void k_dp(const unsigned short* __restrict__ negh, float* __restrict__ dur,
          int* __restrict__ idx_out, const float* __restrict__ x_mask,
          unsigned long long* __restrict__ gbits_all) {
  __shared__ unsigned short ringh[8][4][KROWS * 64];  // 65536 B per-wave ring
  __shared__ float bndlds[3][8][KROWS];               //  1536 B boundary ring
  int b = blockIdx.x, tid = threadIdx.x;
  int lane = tid & 63, w = tid >> 6;
  // wave w's slice stream: blocks of 1024 ushorts per (window, wave)
  const unsigned short* nb =
      negh + (((size_t)b * NWIN) * 8 + w) * 1024 + lane * 8;
  unsigned long long* gbits = gbits_all + (size_t)b * 8 * TFEAT;  // [8][2048]

  if (tid < 3 * 8 * KROWS) ((float*)bndlds)[tid] = NEGINF;

  auto stage = [&](int j) {               // 2 contiguous 1KB loads
    int slot = j & 3;
    const unsigned short* s0 = nb + (size_t)j * 8 * 1024;
    gload_lds16h(s0,       &ringh[w][slot][0]);
    gload_lds16h(s0 + 512, &ringh[w][slot][512]);
  };

  stage(0); stage(1); stage(2);
  __syncthreads();                        // drains prologue loads + bndlds init

  float prev = NEGINF;
  for (int p = 0; p < NWIN + 8; ++p) {
    int i = p - w;                        // this wave's window this phase
    if (i >= 0 && i + 3 < NWIN) { stage(i + 3); VMCNT(6); }
    else if (i >= 0) {
      int rem = NWIN - 1 - i;
      if (rem == 2)      VMCNT(4);
      else if (rem == 1) VMCNT(2);
      else               VMCNT(0);
    }
    asm volatile("s_waitcnt lgkmcnt(0)" ::: "memory");
    __builtin_amdgcn_s_barrier();         // bndlds(prev phase) visible
    __builtin_amdgcn_sched_barrier(0);

    if (i >= 0 && i < NWIN) {
      // hoisted boundary values (wave-uniform)
      float s_bnd[KROWS];
      if (w > 0) {
        float v   = bndlds[i % 3][w - 1][lane & 15];
        float v15 = bndlds[(i + 2) % 3][w - 1][15];
        s_bnd[0] = __int_as_float(__builtin_amdgcn_readfirstlane(__float_as_int(v15)));
        #pragma unroll
        for (int r = 1; r < KROWS; ++r)
          s_bnd[r] = __int_as_float(__builtin_amdgcn_readlane(__float_as_int(v), r - 1));
      } else {
        #pragma unroll
        for (int r = 0; r < KROWS; ++r) s_bnd[r] = NEGINF;
        if (i == 0) s_bnd[0] = 0.0f;      // y==0, x==0 edge
      }
      // own-slice nf: bf16 -> f32 exact decode
      float cur[KROWS];
      #pragma unroll
      for (int r = 0; r < KROWS; ++r)
        cur[r] = __uint_as_float((unsigned)ringh[w][i & 3][r * 64 + lane] << 16);

      int y0 = i * KROWS;
      bool masked = (i < NMASKW);
      unsigned keep_lo = 0, keep_hi = 0;
      float bkeep = 0.0f;
      unsigned long long andm = (w == 0) ? ~1ull : ~0ull;   // x==0 never moves
      #pragma unroll
      for (int r = 0; r < KROWS; ++r) {
        float upd = dpp_shr1(prev);
        float up = (lane == 0) ? s_bnd[r] : upd;
        bool force = masked && (tid == y0 + r);
        bool gt = prev < up;
        unsigned long long m = __ballot(force || gt) & andm;  // uniform
        bool mine = (lane == r);
        keep_lo = mine ? (unsigned)m : keep_lo;
        keep_hi = mine ? (unsigned)(m >> 32) : keep_hi;
        float vc = force ? NEGINF : prev;
        prev = fmaxf(vc, up) + cur[r];
        float v63 = __int_as_float(
            __builtin_amdgcn_readlane(__float_as_int(prev), 63));  // uniform
        bkeep = mine ? v63 : bkeep;
      }
      if (lane < KROWS) {                 // one exec toggle per window
        bndlds[i % 3][w][lane] = bkeep;
        gbits[(size_t)w * TFEAT + y0 + lane] =
            ((unsigned long long)keep_hi << 32) | keep_lo;   // 128B contiguous
      }
    }
  }
  VMCNT(0);
  __syncthreads();                        // gbits stores drained + visible

  // ---- serial backtrack (tid 0), 16-deep register ring over global bits.
  if (tid == 0) {
    const float* xm = x_mask + (size_t)b * TTXT;
    int idx = TTXT - 1, cnt = 0;
    unsigned long long ua[16], ub[16]; int qi[16];
    #pragma unroll
    for (int q16 = 0; q16 < 16; ++q16) {  // rows 2032..2047 (slot = y&15)
      ua[q16] = gbits[(size_t)7 * TFEAT + 2032 + q16];
      ub[q16] = gbits[(size_t)6 * TFEAT + 2032 + q16];
      qi[q16] = 7;
    }
    for (int yb = 2032; yb >= 16; yb -= 16) {
      #pragma unroll
      for (int jj = 15; jj >= 0; --jj) {
        int y = yb + jj;                  // slot = jj (yb % 16 == 0)
        unsigned long long w64 = ((idx >> 6) == qi[jj]) ? ua[jj] : ub[jj];
        idx_out[b * TFEAT + y] = idx;
        cnt++;
        if ((w64 >> (idx & 63)) & 1ull) {
          dur[b * TTXT + idx] = (float)cnt * xm[idx];
          cnt = 0; idx--;
        }
        int q = idx >> 6;                 // refill slot jj for row y-16
        int qm = q > 0 ? q - 1 : 0;
        ua[jj] = gbits[(size_t)q  * TFEAT + (y - 16)];
        ub[jj] = gbits[(size_t)qm * TFEAT + (y - 16)];
        qi[jj] = q;
      }
    }
    #pragma unroll
    for (int jj = 15; jj >= 0; --jj) {    // tail rows 15..0
      int y = jj;
      unsigned long long w64 = ((idx >> 6) == qi[jj]) ? ua[jj] : ub[jj];
      idx_out[b * TFEAT + y] = idx;
      cnt++;
      if ((w64 >> (idx & 63)) & 1ull) {
        dur[b * TTXT + idx] = (float)cnt * xm[idx];
        cnt = 0; idx--;
      }
    }
    dur[b * TTXT] = (float)cnt * xm[0];   // idx == 0 tail run
  }
}

// ---------------------------------------------------------------------------
// Kernel D: attn[b,y,x] = (x == idx[y]) * x_mask[b,x] * y_mask[b,y]
// ---------------------------------------------------------------------------
__global__ void k_attn(const int* __restrict__ idx_arr,
                       const float* __restrict__ x_mask,
                       const float* __restrict__ y_mask,
                       float* __restrict__ attn) {
  size_t gid = (size_t)blockIdx.x * 256 + threadIdx.x;
  size_t e = gid << 2;               // 4 floats per thread
  int b = (int)(e >> 20);            // TFEAT*TTXT = 2^20
  int rem = (int)(e & 1048575u);
  int y = rem >> 9;
  int x0 = rem & 511;
  int idx = idx_arr[b * TFEAT + y];
  float4 v = {0.f, 0.f, 0.f, 0.f};
  int d = idx - x0;
  if (d >= 0 && d < 4) {
    ((float*)&v)[d] = x_mask[b * TTXT + idx] * y_mask[b * TFEAT + y];
  }
  *(float4*)(attn + e) = v;
}

// ---------------------------------------------------------------------------
extern "C" void kernel_launch(void* const* d_in, const int* in_sizes, int n_in,
                              void* d_out, int out_size, void* d_ws, size_t ws_size,
                              hipStream_t stream) {
  const float* z_p    = (const float*)d_in[0];
  const float* m_p    = (const float*)d_in[1];
  const float* logs_p = (const float*)d_in[2];
  const float* x_mask = (const float*)d_in[3];
  const float* y_mask = (const float*)d_in[4];

  float* out  = (float*)d_out;
  float* attn = out;
  float* dur  = out + DUR_OFF;
  float* neg  = out + NEG_OFF;

  // scratch in the attn region (fully rewritten by k_attn at the end):
  //   w1h/w2h (12.6MB bf16 weights) | gbits (4MB) | negh (64MB bf16)
  unsigned short* w1h = (unsigned short*)attn;
  unsigned short* w2h = w1h + (size_t)BATCH * CH * TTXT;   // 3,145,728 ushorts
  unsigned long long* gbits =
      (unsigned long long*)(w2h + (size_t)BATCH * CH * TTXT);
  unsigned short* negh =
      (unsigned short*)((char*)gbits + (size_t)BATCH * 8 * TFEAT * 8);  // +4MB

  // workspace: cadd (64 KiB) + idx array (256 KiB)
  float* cadd = (float*)d_ws;
  int*   idxa = (int*)((char*)d_ws + 65536);

  k_prep<<<(BATCH * CH * TTXT) / 256, 256, 0, stream>>>(m_p, logs_p, w1h, w2h);
  k_cadd<<<(BATCH * TTXT) / 256, 256, 0, stream>>>(m_p, logs_p, cadd);
  k_gemm<<<BATCH * (TFEAT / BM) * (TTXT / BN), 512, 0, stream>>>(z_p, w1h, w2h, cadd, neg, negh);
  k_dp<<<BATCH, 512, 0, stream>>>(negh, dur, idxa, x_mask, gbits);
  k_attn<<<(int)(ATTN_ELEMS / 4 / 256), 256, 0, stream>>>(idxa, x_mask, y_mask, attn);
}

// Round 19
// 511.780 us; speedup vs baseline: 3.1410x; 1.5076x over previous
//
#include <hip/hip_runtime.h>
#include <math.h>

// Problem constants (fixed by the reference setup_inputs)
#define BATCH 32
#define CH    192
#define TFEAT 2048
#define TTXT  512
#define NEGINF (-1e9f)

#define ATTN_ELEMS ((size_t)BATCH * TFEAT * TTXT)   // 33,554,432
#define DUR_OFF    ATTN_ELEMS
#define NEG_OFF    (ATTN_ELEMS + (size_t)BATCH * TTXT)

typedef short bf16x8 __attribute__((ext_vector_type(8)));   // 8 bf16 = 4 VGPR
typedef float f32x16 __attribute__((ext_vector_type(16)));  // 32x32 acc

__device__ __forceinline__ void gload_lds16h(const unsigned short* g,
                                             unsigned short* l) {
  __builtin_amdgcn_global_load_lds(
      (const __attribute__((address_space(1))) void*)g,
      (__attribute__((address_space(3))) void*)l, 16, 0, 0);
}

#define VMCNT(n) asm volatile("s_waitcnt vmcnt(" #n ")" ::: "memory")

__device__ __forceinline__ unsigned short f2b16(float f) {   // RNE bf16
  unsigned u = __float_as_uint(f);
  return (unsigned short)((u + 0x7FFFu + ((u >> 16) & 1u)) >> 16);
}

// ---------------------------------------------------------------------------
// Kernel TA: At2 = fragment-ready bf16 of A = [z | z^2] (M=2048, K=384).
// At2[((b*64+tblk)*24 + kq)*512 + lane*8 + j]; lane = (t&31) + 32*((k>>3)&1),
// k = kq*16 + ((lane>>5)*8) + j; value = k<192 ? z[b][k][t] : z[b][k-192][t]^2.
// One block per (b, tblk=t/32); LDS transpose tile.
// ---------------------------------------------------------------------------
__global__ __launch_bounds__(256)
void k_transA(const float* __restrict__ z_p, unsigned short* __restrict__ At2) {
  __shared__ float zt[CH][33];
  int b = blockIdx.x >> 6, tblk = blockIdx.x & 63;
  int tid = threadIdx.x;
  int t0 = tblk * 32;
  for (int i = tid; i < CH * 32; i += 256) {
    int c = i >> 5, m = i & 31;
    zt[c][m] = z_p[((size_t)b * CH + c) * TFEAT + t0 + m];
  }
  __syncthreads();
  unsigned short* out = At2 + (size_t)(b * 64 + tblk) * 24 * 512;
  for (int o = tid; o < 24 * 512; o += 256) {
    int kq = o >> 9, rem = o & 511;
    int lane = rem >> 3, j = rem & 7;
    int m = lane & 31, kh = lane >> 5;
    int k = kq * 16 + kh * 8 + j;
    float f;
    if (k < CH) f = zt[k][m];
    else { float z = zt[k - CH][m]; f = z * z; }
    out[o] = f2b16(f);
  }
}

// ---------------------------------------------------------------------------
// Kernel TB: Bt2 = fragment-ready bf16 of B = [W1 ; W2] (K=384, N=512).
// W1 = m*exp(-2*logs), W2 = -0.5*exp(-2*logs).
// Bt2[((b*16+sblk)*24 + kq)*512 + lane*8 + j]; lane = (s&31) + 32*((k>>3)&1).
// ---------------------------------------------------------------------------
__global__ __launch_bounds__(256)
void k_transB(const float* __restrict__ m_p, const float* __restrict__ logs_p,
              unsigned short* __restrict__ Bt2) {
  __shared__ float w1t[CH][33];
  __shared__ float w2t[CH][33];
  int b = blockIdx.x >> 4, sblk = blockIdx.x & 15;
  int tid = threadIdx.x;
  int s0 = sblk * 32;
  for (int i = tid; i < CH * 32; i += 256) {
    int c = i >> 5, n = i & 31;
    size_t idx = ((size_t)b * CH + c) * TTXT + s0 + n;
    float m = m_p[idx];
    float r = __expf(-2.0f * logs_p[idx]);
    w1t[c][n] = m * r;
    w2t[c][n] = -0.5f * r;
  }
  __syncthreads();
  unsigned short* out = Bt2 + (size_t)(b * 16 + sblk) * 24 * 512;
  for (int o = tid; o < 24 * 512; o += 256) {
    int kq = o >> 9, rem = o & 511;
    int lane = rem >> 3, j = rem & 7;
    int n = lane & 31, kh = lane >> 5;
    int k = kq * 16 + kh * 8 + j;
    float f = (k < CH) ? w1t[k][n] : w2t[k - CH][n];
    out[o] = f2b16(f);
  }
}

// ---------------------------------------------------------------------------
// Kernel A: cadd[b][s] = sum_c(-0.5*log(2pi) - logs) + sum_c(-0.5*m^2*r)
// (full f32 precision — the additive part stays exact)
// ---------------------------------------------------------------------------
__global__ void k_cadd(const float* __restrict__ m_p,
                       const float* __restrict__ logs_p,
                       float* __restrict__ cadd) {
  int gid = blockIdx.x * 256 + threadIdx.x;        // 0 .. 16383
  int b = gid >> 9, s = gid & (TTXT - 1);
  const float* mp = m_p    + (size_t)b * CH * TTXT + s;
  const float* lp = logs_p + (size_t)b * CH * TTXT + s;
  float acc = -0.5f * 1.8378770664093453f * (float)CH;   // -C/2 * log(2*pi)
  #pragma unroll 4
  for (int c = 0; c < CH; ++c) {
    float l = lp[(size_t)c * TTXT];
    float m = mp[(size_t)c * TTXT];
    float r = __expf(-2.0f * l);
    acc -= l + 0.5f * m * m * r;
  }
  cadd[gid] = acc;
}

// ---------------------------------------------------------------------------
// Kernel B (R19): bf16 MFMA GEMM — neg = A(2048x384) x B(384x512) + cadd.
// R18 evidence: bf16-rounded inputs pass (absmax 1024 << 3276.8). No LDS,
// no barriers: frags stream from fragment-ready At2/Bt2 via coalesced
// dwordx4; 8 waves x 64x64 tiles (2x2 of 32x32), 96 mfma_f32_32x32x16_bf16
// per wave, depth-1 named rotation + sched_barrier(0) (anti-spill).
// C/D layout (m74/m101 verified): col=lane&31, row=(reg&3)+8*(reg>>2)+4*(lane>>5).
// ---------------------------------------------------------------------------
__global__ __launch_bounds__(512)
void k_mf(const unsigned short* __restrict__ At2,
          const unsigned short* __restrict__ Bt2,
          const float* __restrict__ cadd,
          float* __restrict__ neg,
          unsigned short* __restrict__ negh) {
  // XCD swizzle (1024 blocks, 8 XCDs, 128 per chunk; bijective)
  int blk = (blockIdx.x & 7) * 128 + (blockIdx.x >> 3);
  int sb = blk & 1;            // 512/256 = 2 col-blocks
  int tb = (blk >> 1) & 15;    // 2048/128 = 16 row-blocks
  int b  = blk >> 5;
  int tid = threadIdx.x, lane = tid & 63, w = tid >> 6;
  int rg = w >> 2, cg = w & 3;
  int trow0 = tb * 128 + rg * 64;
  int scol0 = sb * 256 + cg * 64;

  const unsigned short* ap0 = At2 + ((size_t)(b * 64 + (trow0 >> 5)) * 24) * 512 + lane * 8;
  const unsigned short* ap1 = ap0 + (size_t)24 * 512;          // next 32-row tile
  const unsigned short* bp0 = Bt2 + ((size_t)(b * 16 + (scol0 >> 5)) * 24) * 512 + lane * 8;
  const unsigned short* bp1 = bp0 + (size_t)24 * 512;          // next 32-col tile

  f32x16 acc00, acc01, acc10, acc11;
  #pragma unroll
  for (int r = 0; r < 16; ++r) { acc00[r] = 0.f; acc01[r] = 0.f; acc10[r] = 0.f; acc11[r] = 0.f; }

  bf16x8 a0A, a1A, b0A, b1A;   // set A
  bf16x8 a0B, a1B, b0B, b1B;   // set B

  auto LDA = [&](bf16x8& x0, bf16x8& x1, bf16x8& y0, bf16x8& y1, int kq) {
    x0 = *(const bf16x8*)(ap0 + (size_t)kq * 512);
    x1 = *(const bf16x8*)(ap1 + (size_t)kq * 512);
    y0 = *(const bf16x8*)(bp0 + (size_t)kq * 512);
    y1 = *(const bf16x8*)(bp1 + (size_t)kq * 512);
  };
  auto FMA = [&](bf16x8& x0, bf16x8& x1, bf16x8& y0, bf16x8& y1) {
    acc00 = __builtin_amdgcn_mfma_f32_32x32x16_bf16(x0, y0, acc00, 0, 0, 0);
    acc01 = __builtin_amdgcn_mfma_f32_32x32x16_bf16(x0, y1, acc01, 0, 0, 0);
    acc10 = __builtin_amdgcn_mfma_f32_32x32x16_bf16(x1, y0, acc10, 0, 0, 0);
    acc11 = __builtin_amdgcn_mfma_f32_32x32x16_bf16(x1, y1, acc11, 0, 0, 0);
  };

  LDA(a0A, a1A, b0A, b1A, 0);
  #pragma unroll
  for (int kq = 0; kq < 24; kq += 2) {
    LDA(a0B, a1B, b0B, b1B, kq + 1);     // hides under FMA(set A)
    FMA(a0A, a1A, b0A, b1A);
    __builtin_amdgcn_sched_barrier(0);   // cap pipeline depth (anti-spill)
    if (kq + 2 < 24) LDA(a0A, a1A, b0A, b1A, kq + 2);
    FMA(a0B, a1B, b0B, b1B);
    __builtin_amdgcn_sched_barrier(0);
  }

  // epilogue: + cadd, store neg (f32) + negh (bf16, k_dp's re-tiled layout)
  #pragma unroll
  for (int ti = 0; ti < 2; ++ti) {
    #pragma unroll
    for (int tj = 0; tj < 2; ++tj) {
      const f32x16& v = (ti == 0) ? ((tj == 0) ? acc00 : acc01)
                                  : ((tj == 0) ? acc10 : acc11);
      int s = scol0 + tj * 32 + (lane & 31);
      float cv = cadd[b * TTXT + s];
      int tB = trow0 + ti * 32 + 4 * (lane >> 5);
      float* np_ = neg + (size_t)b * TFEAT * TTXT + s;
      #pragma unroll
      for (int r = 0; r < 16; ++r) {
        int t = tB + (r & 3) + 8 * (r >> 2);
        float o = v[r] + cv;
        np_[(size_t)t * TTXT] = o;
        negh[(((size_t)b * 128 + (t >> 4)) * 8 + (s >> 6)) * 1024
             + (t & 15) * 64 + (s & 63)] = f2b16(o);
      }
    }
  }
}

// ---------------------------------------------------------------------------
// Kernel C: skewed-wavefront DP — UNCHANGED from R16 (~290us, frozen).
// ---------------------------------------------------------------------------
#define KROWS 16
#define NWIN  (TFEAT / KROWS)     // 128 windows
#define NMASKW (TTXT / KROWS)     // 32 masked windows

__device__ __forceinline__ float dpp_shr1(float v) {
  return __int_as_float(__builtin_amdgcn_update_dpp(
      __float_as_int(v), __float_as_int(v), 0x138 /*wave_shr:1*/, 0xF, 0xF, false));
}

__global__ __launch_bounds__(512, 1)
void k_dp(const unsigned short* __restrict__ negh, float* __restrict__ dur,
          int* __restrict__ idx_out, const float* __restrict__ x_mask,
          unsigned long long* __restrict__ gbits_all) {
  __shared__ unsigned short ringh[8][4][KROWS * 64];  // 65536 B per-wave ring
  __shared__ float bndlds[3][8][KROWS];               //  1536 B boundary ring
  int b = blockIdx.x, tid = threadIdx.x;
  int lane = tid & 63, w = tid >> 6;
  // wave w's slice stream: blocks of 1024 ushorts per (window, wave)
  const unsigned short* nb =
      negh + (((size_t)b * NWIN) * 8 + w) * 1024 + lane * 8;
  unsigned long long* gbits = gbits_all + (size_t)b * 8 * TFEAT;  // [8][2048]

  if (tid < 3 * 8 * KROWS) ((float*)bndlds)[tid] = NEGINF;

  auto stage = [&](int j) {               // 2 contiguous 1KB loads
    int slot = j & 3;
    const unsigned short* s0 = nb + (size_t)j * 8 * 1024;
    gload_lds16h(s0,       &ringh[w][slot][0]);
    gload_lds16h(s0 + 512, &ringh[w][slot][512]);
  };

  stage(0); stage(1); stage(2);
  __syncthreads();                        // drains prologue loads + bndlds init

  float prev = NEGINF;
  for (int p = 0; p < NWIN + 8; ++p) {
    int i = p - w;                        // this wave's window this phase
    if (i >= 0 && i + 3 < NWIN) { stage(i + 3); VMCNT(6); }
    else if (i >= 0) {
      int rem = NWIN - 1 - i;
      if (rem == 2)      VMCNT(4);
      else if (rem == 1) VMCNT(2);
      else               VMCNT(0);
    }
    asm volatile("s_waitcnt lgkmcnt(0)" ::: "memory");
    __builtin_amdgcn_s_barrier();         // bndlds(prev phase) visible
    __builtin_amdgcn_sched_barrier(0);

    if (i >= 0 && i < NWIN) {
      // hoisted boundary values (wave-uniform)
      float s_bnd[KROWS];
      if (w > 0) {
        float v   = bndlds[i % 3][w - 1][lane & 15];
        float v15 = bndlds[(i + 2) % 3][w - 1][15];
        s_bnd[0] = __int_as_float(__builtin_amdgcn_readfirstlane(__float_as_int(v15)));
        #pragma unroll
        for (int r = 1; r < KROWS; ++r)
          s_bnd[r] = __int_as_float(__builtin_amdgcn_readlane(__float_as_int(v), r - 1));
      } else {
        #pragma unroll
        for (int r = 0; r < KROWS; ++r) s_bnd[r] = NEGINF;
        if (i == 0) s_bnd[0] = 0.0f;      // y==0, x==0 edge
      }
      // own-slice nf: bf16 -> f32 exact decode
      float cur[KROWS];
      #pragma unroll
      for (int r = 0; r < KROWS; ++r)
        cur[r] = __uint_as_float((unsigned)ringh[w][i & 3][r * 64 + lane] << 16);

      int y0 = i * KROWS;
      bool masked = (i < NMASKW);
      unsigned keep_lo = 0, keep_hi = 0;
      float bkeep = 0.0f;
      unsigned long long andm = (w == 0) ? ~1ull : ~0ull;   // x==0 never moves
      #pragma unroll
      for (int r = 0; r < KROWS; ++r) {
        float upd = dpp_shr1(prev);
        float up = (lane == 0) ? s_bnd[r] : upd;
        bool force = masked && (tid == y0 + r);
        bool gt = prev < up;
        unsigned long long m = __ballot(force || gt) & andm;  // uniform
        bool mine = (lane == r);
        keep_lo = mine ? (unsigned)m : keep_lo;
        keep_hi = mine ? (unsigned)(m >> 32) : keep_hi;
        float vc = force ? NEGINF : prev;
        prev = fmaxf(vc, up) + cur[r];
        float v63 = __int_as_float(
            __builtin_amdgcn_readlane(__float_as_int(prev), 63));  // uniform
        bkeep = mine ? v63 : bkeep;
      }
      if (lane < KROWS) {                 // one exec toggle per window
        bndlds[i % 3][w][lane] = bkeep;
        gbits[(size_t)w * TFEAT + y0 + lane] =
            ((unsigned long long)keep_hi << 32) | keep_lo;   // 128B contiguous
      }
    }
  }
  VMCNT(0);
  __syncthreads();                        // gbits stores drained + visible

  // ---- serial backtrack (tid 0), 16-deep register ring over global bits.
  if (tid == 0) {
    const float* xm = x_mask + (size_t)b * TTXT;
    int idx = TTXT - 1, cnt = 0;
    unsigned long long ua[16], ub[16]; int qi[16];
    #pragma unroll
    for (int q16 = 0; q16 < 16; ++q16) {  // rows 2032..2047 (slot = y&15)
      ua[q16] = gbits[(size_t)7 * TFEAT + 2032 + q16];
      ub[q16] = gbits[(size_t)6 * TFEAT + 2032 + q16];
      qi[q16] = 7;
    }
    for (int yb = 2032; yb >= 16; yb -= 16) {
      #pragma unroll
      for (int jj = 15; jj >= 0; --jj) {
        int y = yb + jj;                  // slot = jj (yb % 16 == 0)
        unsigned long long w64 = ((idx >> 6) == qi[jj]) ? ua[jj] : ub[jj];
        idx_out[b * TFEAT + y] = idx;
        cnt++;
        if ((w64 >> (idx & 63)) & 1ull) {
          dur[b * TTXT + idx] = (float)cnt * xm[idx];
          cnt = 0; idx--;
        }
        int q = idx >> 6;                 // refill slot jj for row y-16
        int qm = q > 0 ? q - 1 : 0;
        ua[jj] = gbits[(size_t)q  * TFEAT + (y - 16)];
        ub[jj] = gbits[(size_t)qm * TFEAT + (y - 16)];
        qi[jj] = q;
      }
    }
    #pragma unroll
    for (int jj = 15; jj >= 0; --jj) {    // tail rows 15..0
      int y = jj;
      unsigned long long w64 = ((idx >> 6) == qi[jj]) ? ua[jj] : ub[jj];
      idx_out[b * TFEAT + y] = idx;
      cnt++;
      if ((w64 >> (idx & 63)) & 1ull) {
        dur[b * TTXT + idx] = (float)cnt * xm[idx];
        cnt = 0; idx--;
      }
    }
    dur[b * TTXT] = (float)cnt * xm[0];   // idx == 0 tail run
  }
}

// ---------------------------------------------------------------------------
// Kernel D: attn[b,y,x] = (x == idx[y]) * x_mask[b,x] * y_mask[b,y]
// ---------------------------------------------------------------------------
__global__ void k_attn(const int* __restrict__ idx_arr,
                       const float* __restrict__ x_mask,
                       const float* __restrict__ y_mask,
                       float* __restrict__ attn) {
  size_t gid = (size_t)blockIdx.x * 256 + threadIdx.x;
  size_t e = gid << 2;               // 4 floats per thread
  int b = (int)(e >> 20);            // TFEAT*TTXT = 2^20
  int rem = (int)(e & 1048575u);
  int y = rem >> 9;
  int x0 = rem & 511;
  int idx = idx_arr[b * TFEAT + y];
  float4 v = {0.f, 0.f, 0.f, 0.f};
  int d = idx - x0;
  if (d >= 0 && d < 4) {
    ((float*)&v)[d] = x_mask[b * TTXT + idx] * y_mask[b * TFEAT + y];
  }
  *(float4*)(attn + e) = v;
}

// ---------------------------------------------------------------------------
extern "C" void kernel_launch(void* const* d_in, const int* in_sizes, int n_in,
                              void* d_out, int out_size, void* d_ws, size_t ws_size,
                              hipStream_t stream) {
  const float* z_p    = (const float*)d_in[0];
  const float* m_p    = (const float*)d_in[1];
  const float* logs_p = (const float*)d_in[2];
  const float* x_mask = (const float*)d_in[3];
  const float* y_mask = (const float*)d_in[4];

  float* out  = (float*)d_out;
  float* attn = out;
  float* dur  = out + DUR_OFF;
  float* neg  = out + NEG_OFF;

  // scratch in the attn region (134,217,728 B; fully rewritten by k_attn):
  //   gbits 4MB | negh 64MB | At2 48MB | Bt2 12MB  (exact fit)
  char* scr = (char*)attn;
  unsigned long long* gbits = (unsigned long long*)scr;
  unsigned short* negh = (unsigned short*)(scr + 4194304);
  unsigned short* At2  = (unsigned short*)(scr + 71303168);
  unsigned short* Bt2  = (unsigned short*)(scr + 121634816);

  // workspace: cadd (64 KiB) + idx array (256 KiB)
  float* cadd = (float*)d_ws;
  int*   idxa = (int*)((char*)d_ws + 65536);

  k_transA<<<BATCH * 64, 256, 0, stream>>>(z_p, At2);
  k_transB<<<BATCH * 16, 256, 0, stream>>>(m_p, logs_p, Bt2);
  k_cadd<<<(BATCH * TTXT) / 256, 256, 0, stream>>>(m_p, logs_p, cadd);
  k_mf<<<1024, 512, 0, stream>>>(At2, Bt2, cadd, neg, negh);
  k_dp<<<BATCH, 512, 0, stream>>>(negh, dur, idxa, x_mask, gbits);
  k_attn<<<(int)(ATTN_ELEMS / 4 / 256), 256, 0, stream>>>(idxa, x_mask, y_mask, attn);
}